// Round 1
// baseline (2160.611 us; speedup 1.0000x reference)
//
#include <hip/hip_runtime.h>

#define WW 12
#define CH 32    // CIN == CMID == COUT == 32
#define KERN 3

// ---------------------------------------------------------------------------
// K1: deg[dst] += Ew  (segment_sum over edges)
__global__ void deg_kernel(const int* __restrict__ dst, const float* __restrict__ Ew,
                           float* __restrict__ deg, int E) {
  int e = blockIdx.x * blockDim.x + threadIdx.x;
  if (e < E) atomicAdd(&deg[dst[e]], Ew[e]);
}

// K2: deg -> dinv in place
__global__ void dinv_kernel(float* __restrict__ deg, int N) {
  int n = blockIdx.x * blockDim.x + threadIdx.x;
  if (n < N) {
    float d = deg[n];
    deg[n] = (d > 0.f) ? rsqrtf(fmaxf(d, 1e-12f)) : 0.f;
  }
}

// K3: w_hat[e] = -dinv[src]*Ew*dinv[dst]
__global__ void what_kernel(const int* __restrict__ src, const int* __restrict__ dst,
                            const float* __restrict__ Ew, const float* __restrict__ dinv,
                            float* __restrict__ what, int E) {
  int e = blockIdx.x * blockDim.x + threadIdx.x;
  if (e < E) what[e] = -dinv[src[e]] * Ew[e] * dinv[dst[e]];
}

// K4: per (w,n):  h = bcheb[w] + x@Wcheb[w,0];  y = x@Wcheb[w,1]
__global__ void cheb_kernel(const float* __restrict__ x, const float* __restrict__ Wcheb,
                            const float* __restrict__ bcheb,
                            float* __restrict__ h, float* __restrict__ y, int N) {
  __shared__ float W0[CH][CH];
  __shared__ float W1[CH][CH];
  __shared__ float bs[CH];
  const int w = blockIdx.y;
  const int tid = threadIdx.x;
  for (int i = tid; i < CH * CH; i += blockDim.x) {
    W0[i >> 5][i & 31] = Wcheb[(size_t)(w * 2 + 0) * CH * CH + i];
    W1[i >> 5][i & 31] = Wcheb[(size_t)(w * 2 + 1) * CH * CH + i];
  }
  if (tid < CH) bs[tid] = bcheb[w * CH + tid];
  __syncthreads();

  const int n = blockIdx.x * blockDim.x + tid;
  if (n >= N) return;

  const float4* xp = (const float4*)(x + ((size_t)w * N + n) * CH);
  float xv[CH];
#pragma unroll
  for (int i = 0; i < CH / 4; ++i) {
    float4 v = xp[i];
    xv[4 * i + 0] = v.x; xv[4 * i + 1] = v.y; xv[4 * i + 2] = v.z; xv[4 * i + 3] = v.w;
  }

  float ha[CH], ya[CH];
#pragma unroll
  for (int d = 0; d < CH; ++d) { ha[d] = bs[d]; ya[d] = 0.f; }
#pragma unroll
  for (int c = 0; c < CH; ++c) {
    float xc = xv[c];
#pragma unroll
    for (int d = 0; d < CH; ++d) {
      ha[d] += xc * W0[c][d];
      ya[d] += xc * W1[c][d];
    }
  }

  float4* hp = (float4*)(h + ((size_t)w * N + n) * CH);
  float4* yp = (float4*)(y + ((size_t)w * N + n) * CH);
#pragma unroll
  for (int i = 0; i < CH / 4; ++i) {
    hp[i] = make_float4(ha[4 * i], ha[4 * i + 1], ha[4 * i + 2], ha[4 * i + 3]);
    yp[i] = make_float4(ya[4 * i], ya[4 * i + 1], ya[4 * i + 2], ya[4 * i + 3]);
  }
}

// K5: h[w, dst, c] += w_hat[e] * y[w, src, c]   (atomics; 32 lanes = one edge)
__global__ void prop_kernel(const int* __restrict__ src, const int* __restrict__ dst,
                            const float* __restrict__ what, const float* __restrict__ y,
                            float* __restrict__ h, int N, int E) {
  long long t = (long long)blockIdx.x * blockDim.x + threadIdx.x;
  int e = (int)(t >> 5);
  int c = (int)(t & 31);
  if (e >= E) return;
  int s = src[e], d = dst[e];
  float wh = what[e];
  size_t so = (size_t)s * CH + c;
  size_t dofs = (size_t)d * CH + c;
  const size_t plane = (size_t)N * CH;
#pragma unroll
  for (int w = 0; w < WW; ++w) {
    float v = wh * y[(size_t)w * plane + so];
    atomicAdd(&h[(size_t)w * plane + dofs], v);
  }
}

// K6: temporal conv (KER=3, pad 1) over W + bias + leaky ReLU -> out (N, W, COUT)
__global__ void conv_kernel(const float* __restrict__ h, const float* __restrict__ Wconv,
                            const float* __restrict__ bconv, float* __restrict__ out, int N) {
  __shared__ float Wc[KERN][CH][CH];  // [k][c][o]
  __shared__ float bc[CH];
  const int tid = threadIdx.x;
  for (int i = tid; i < KERN * CH * CH; i += blockDim.x) {
    int k = i / (CH * CH);
    int rem = i % (CH * CH);
    int c = rem / CH;
    int o = rem % CH;
    Wc[k][c][o] = Wconv[(o * CH + c) * KERN + k];
  }
  if (tid < CH) bc[tid] = bconv[tid];
  __syncthreads();

  long long id = (long long)blockIdx.x * blockDim.x + tid;
  if (id >= (long long)N * WW) return;
  int n = (int)(id / WW);
  int t = (int)(id % WW);

  float acc[CH];
#pragma unroll
  for (int o = 0; o < CH; ++o) acc[o] = bc[o];

#pragma unroll
  for (int k = 0; k < KERN; ++k) {
    int tt = t + k - 1;
    if (tt < 0 || tt >= WW) continue;
    const float4* hp = (const float4*)(h + ((size_t)tt * N + n) * CH);
    float hv[CH];
#pragma unroll
    for (int i = 0; i < CH / 4; ++i) {
      float4 v = hp[i];
      hv[4 * i + 0] = v.x; hv[4 * i + 1] = v.y; hv[4 * i + 2] = v.z; hv[4 * i + 3] = v.w;
    }
#pragma unroll
    for (int c = 0; c < CH; ++c) {
      float x = hv[c];
#pragma unroll
      for (int o = 0; o < CH; ++o) acc[o] += x * Wc[k][c][o];
    }
  }

  float4* op = (float4*)(out + (size_t)id * CH);
#pragma unroll
  for (int i = 0; i < CH / 4; ++i) {
    float a0 = acc[4 * i + 0], a1 = acc[4 * i + 1], a2 = acc[4 * i + 2], a3 = acc[4 * i + 3];
    a0 = (a0 >= 0.f) ? a0 : 0.01f * a0;
    a1 = (a1 >= 0.f) ? a1 : 0.01f * a1;
    a2 = (a2 >= 0.f) ? a2 : 0.01f * a2;
    a3 = (a3 >= 0.f) ? a3 : 0.01f * a3;
    op[i] = make_float4(a0, a1, a2, a3);
  }
}

// ---------------------------------------------------------------------------
extern "C" void kernel_launch(void* const* d_in, const int* in_sizes, int n_in,
                              void* d_out, int out_size, void* d_ws, size_t ws_size,
                              hipStream_t stream) {
  const float* x     = (const float*)d_in[0];
  const int*   A     = (const int*)d_in[1];
  const float* Ew    = (const float*)d_in[2];
  const float* Wcheb = (const float*)d_in[3];
  const float* bcheb = (const float*)d_in[4];
  const float* Wconv = (const float*)d_in[5];
  const float* bconv = (const float*)d_in[6];
  float* out = (float*)d_out;

  const int E = in_sizes[2];
  const int N = in_sizes[0] / (WW * CH);
  const int* srcA = A;
  const int* dstA = A + E;

  char* ws = (char*)d_ws;
  size_t off = 0;
  auto alloc = [&](size_t bytes) -> void* {
    void* p = ws + off;
    off += (bytes + 255) / 256 * 256;
    return p;
  };
  float* deg  = (float*)alloc((size_t)N * 4);
  float* what = (float*)alloc((size_t)E * 4);
  float* y    = (float*)alloc((size_t)WW * N * CH * 4);
  float* h    = (float*)alloc((size_t)WW * N * CH * 4);
  (void)ws_size;

  hipMemsetAsync(deg, 0, (size_t)N * 4, stream);

  deg_kernel<<<(E + 255) / 256, 256, 0, stream>>>(dstA, Ew, deg, E);
  dinv_kernel<<<(N + 255) / 256, 256, 0, stream>>>(deg, N);
  what_kernel<<<(E + 255) / 256, 256, 0, stream>>>(srcA, dstA, Ew, deg, what, E);

  dim3 gcheb((N + 255) / 256, WW);
  cheb_kernel<<<gcheb, 256, 0, stream>>>(x, Wcheb, bcheb, h, y, N);

  long long ptot = (long long)E * 32;
  prop_kernel<<<(unsigned)((ptot + 255) / 256), 256, 0, stream>>>(srcA, dstA, what, y, h, N, E);

  long long ctot = (long long)N * WW;
  conv_kernel<<<(unsigned)((ctot + 255) / 256), 256, 0, stream>>>(h, Wconv, bconv, out, N);
}

// Round 2
// 964.613 us; speedup vs baseline: 2.2399x; 2.2399x over previous
//
#include <hip/hip_runtime.h>

#define WW 12
#define CH 32    // CIN == CMID == COUT == 32
#define KERN 3
#define SCAN_T 1024

// ---------------------------------------------------------------------------
// K1: deg[dst] += Ew  and  cnt[dst] += 1
__global__ void degcnt_kernel(const int* __restrict__ dst, const float* __restrict__ Ew,
                              float* __restrict__ deg, int* __restrict__ cnt, int E) {
  int e = blockIdx.x * blockDim.x + threadIdx.x;
  if (e < E) {
    int d = dst[e];
    atomicAdd(&deg[d], Ew[e]);
    atomicAdd(&cnt[d], 1);
  }
}

// K2: deg -> dinv in place
__global__ void dinv_kernel(float* __restrict__ deg, int N) {
  int n = blockIdx.x * blockDim.x + threadIdx.x;
  if (n < N) {
    float d = deg[n];
    deg[n] = (d > 0.f) ? rsqrtf(fmaxf(d, 1e-12f)) : 0.f;
  }
}

// K3: single-block exclusive scan of cnt -> rowptr[0..N], wptr copy
__global__ void scan_kernel(const int* __restrict__ cnt, int* __restrict__ rowptr,
                            int* __restrict__ wptr, int N) {
  __shared__ int tmp[SCAN_T];
  __shared__ int carry_s;
  const int tid = threadIdx.x;
  if (tid == 0) carry_s = 0;
  __syncthreads();
  for (int base = 0; base < N; base += SCAN_T) {
    int i = base + tid;
    int v = (i < N) ? cnt[i] : 0;
    tmp[tid] = v;
    __syncthreads();
    for (int ofs = 1; ofs < SCAN_T; ofs <<= 1) {
      int t = (tid >= ofs) ? tmp[tid - ofs] : 0;
      __syncthreads();
      tmp[tid] += t;
      __syncthreads();
    }
    int incl = tmp[tid];
    int carry = carry_s;
    if (i < N) {
      int ex = carry + incl - v;
      rowptr[i] = ex;
      wptr[i] = ex;
    }
    __syncthreads();
    if (tid == SCAN_T - 1) carry_s = carry + incl;
    __syncthreads();
  }
  if (tid == 0) rowptr[N] = carry_s;
}

// K4: scatter edges into CSR slots; compute w_hat inline
__global__ void fill_kernel(const int* __restrict__ src, const int* __restrict__ dst,
                            const float* __restrict__ Ew, const float* __restrict__ dinv,
                            int* __restrict__ wptr, int* __restrict__ srcs_s,
                            float* __restrict__ what_s, int E) {
  int e = blockIdx.x * blockDim.x + threadIdx.x;
  if (e < E) {
    int s = src[e], d = dst[e];
    float wh = -dinv[s] * Ew[e] * dinv[d];
    int pos = atomicAdd(&wptr[d], 1);
    srcs_s[pos] = s;
    what_s[pos] = wh;
  }
}

// K5: gather  z[w,n,c] = sum_{e: dst=n} what[e] * x[w,src[e],c]
//     32 lanes = one node (lane = channel c), 12 w-planes in registers.
__global__ void gather_kernel(const int* __restrict__ rowptr, const int* __restrict__ srcs_s,
                              const float* __restrict__ what_s, const float* __restrict__ x,
                              float* __restrict__ z, int N) {
  int t = blockIdx.x * blockDim.x + threadIdx.x;
  int n = t >> 5;
  if (n >= N) return;
  int c = t & 31;
  const size_t plane = (size_t)N * CH;
  float acc[WW];
#pragma unroll
  for (int w = 0; w < WW; ++w) acc[w] = 0.f;
  int i1 = rowptr[n + 1];
  for (int i = rowptr[n]; i < i1; ++i) {
    int s = srcs_s[i];
    float wh = what_s[i];
    const float* xp = x + (size_t)s * CH + c;
#pragma unroll
    for (int w = 0; w < WW; ++w) acc[w] = fmaf(wh, xp[w * plane], acc[w]);
  }
  float* zp = z + (size_t)n * CH + c;
#pragma unroll
  for (int w = 0; w < WW; ++w) zp[w * plane] = acc[w];
}

// K6: per (w,n):  h = bcheb[w] + x@W0[w] + z@W1[w]   (IN PLACE: zh holds z in, h out)
__global__ void mix_kernel(const float* __restrict__ x, const float* __restrict__ Wcheb,
                           const float* __restrict__ bcheb, float* __restrict__ zh, int N) {
  __shared__ float W0[CH][CH];
  __shared__ float W1[CH][CH];
  __shared__ float bs[CH];
  const int w = blockIdx.y;
  const int tid = threadIdx.x;
  for (int i = tid; i < CH * CH; i += blockDim.x) {
    W0[i >> 5][i & 31] = Wcheb[(size_t)(w * 2 + 0) * CH * CH + i];
    W1[i >> 5][i & 31] = Wcheb[(size_t)(w * 2 + 1) * CH * CH + i];
  }
  if (tid < CH) bs[tid] = bcheb[w * CH + tid];
  __syncthreads();

  const int n = blockIdx.x * blockDim.x + tid;
  if (n >= N) return;

  const float4* xp = (const float4*)(x + ((size_t)w * N + n) * CH);
  float4* zp = (float4*)(zh + ((size_t)w * N + n) * CH);

  float xv[CH], zv[CH];
#pragma unroll
  for (int i = 0; i < CH / 4; ++i) {
    float4 v = xp[i];
    xv[4 * i + 0] = v.x; xv[4 * i + 1] = v.y; xv[4 * i + 2] = v.z; xv[4 * i + 3] = v.w;
    float4 u = zp[i];
    zv[4 * i + 0] = u.x; zv[4 * i + 1] = u.y; zv[4 * i + 2] = u.z; zv[4 * i + 3] = u.w;
  }

  float ha[CH];
#pragma unroll
  for (int d = 0; d < CH; ++d) ha[d] = bs[d];
#pragma unroll
  for (int c = 0; c < CH; ++c) {
    float xc = xv[c];
    float zc = zv[c];
#pragma unroll
    for (int d = 0; d < CH; ++d) {
      ha[d] += xc * W0[c][d] + zc * W1[c][d];
    }
  }

#pragma unroll
  for (int i = 0; i < CH / 4; ++i) {
    zp[i] = make_float4(ha[4 * i], ha[4 * i + 1], ha[4 * i + 2], ha[4 * i + 3]);
  }
}

// K7: temporal conv (KER=3, pad 1) over W + bias + leaky ReLU -> out (N, W, COUT)
__global__ void conv_kernel(const float* __restrict__ h, const float* __restrict__ Wconv,
                            const float* __restrict__ bconv, float* __restrict__ out, int N) {
  __shared__ float Wc[KERN][CH][CH];  // [k][c][o]
  __shared__ float bc[CH];
  const int tid = threadIdx.x;
  for (int i = tid; i < KERN * CH * CH; i += blockDim.x) {
    int k = i / (CH * CH);
    int rem = i % (CH * CH);
    int c = rem / CH;
    int o = rem % CH;
    Wc[k][c][o] = Wconv[(o * CH + c) * KERN + k];
  }
  if (tid < CH) bc[tid] = bconv[tid];
  __syncthreads();

  long long id = (long long)blockIdx.x * blockDim.x + tid;
  if (id >= (long long)N * WW) return;
  int n = (int)(id / WW);
  int t = (int)(id % WW);

  float acc[CH];
#pragma unroll
  for (int o = 0; o < CH; ++o) acc[o] = bc[o];

#pragma unroll
  for (int k = 0; k < KERN; ++k) {
    int tt = t + k - 1;
    if (tt < 0 || tt >= WW) continue;
    const float4* hp = (const float4*)(h + ((size_t)tt * N + n) * CH);
    float hv[CH];
#pragma unroll
    for (int i = 0; i < CH / 4; ++i) {
      float4 v = hp[i];
      hv[4 * i + 0] = v.x; hv[4 * i + 1] = v.y; hv[4 * i + 2] = v.z; hv[4 * i + 3] = v.w;
    }
#pragma unroll
    for (int c = 0; c < CH; ++c) {
      float x = hv[c];
#pragma unroll
      for (int o = 0; o < CH; ++o) acc[o] += x * Wc[k][c][o];
    }
  }

  float4* op = (float4*)(out + (size_t)id * CH);
#pragma unroll
  for (int i = 0; i < CH / 4; ++i) {
    float a0 = acc[4 * i + 0], a1 = acc[4 * i + 1], a2 = acc[4 * i + 2], a3 = acc[4 * i + 3];
    a0 = (a0 >= 0.f) ? a0 : 0.01f * a0;
    a1 = (a1 >= 0.f) ? a1 : 0.01f * a1;
    a2 = (a2 >= 0.f) ? a2 : 0.01f * a2;
    a3 = (a3 >= 0.f) ? a3 : 0.01f * a3;
    op[i] = make_float4(a0, a1, a2, a3);
  }
}

// ---------------------------------------------------------------------------
extern "C" void kernel_launch(void* const* d_in, const int* in_sizes, int n_in,
                              void* d_out, int out_size, void* d_ws, size_t ws_size,
                              hipStream_t stream) {
  const float* x     = (const float*)d_in[0];
  const int*   A     = (const int*)d_in[1];
  const float* Ew    = (const float*)d_in[2];
  const float* Wcheb = (const float*)d_in[3];
  const float* bcheb = (const float*)d_in[4];
  const float* Wconv = (const float*)d_in[5];
  const float* bconv = (const float*)d_in[6];
  float* out = (float*)d_out;

  const int E = in_sizes[2];
  const int N = in_sizes[0] / (WW * CH);
  const int* srcA = A;
  const int* dstA = A + E;

  char* ws = (char*)d_ws;
  size_t off = 0;
  auto alloc = [&](size_t bytes) -> void* {
    void* p = ws + off;
    off += (bytes + 255) / 256 * 256;
    return p;
  };
  float* deg    = (float*)alloc((size_t)N * 4);        // later: dinv
  int*   cnt    = (int*)alloc((size_t)N * 4);
  int*   rowptr = (int*)alloc((size_t)(N + 1) * 4);
  int*   wptr   = (int*)alloc((size_t)N * 4);
  int*   srcs_s = (int*)alloc((size_t)E * 4);
  float* what_s = (float*)alloc((size_t)E * 4);
  float* zh     = (float*)alloc((size_t)WW * N * CH * 4);  // z then h (in place)
  (void)ws_size;

  hipMemsetAsync(deg, 0, (size_t)N * 4, stream);
  hipMemsetAsync(cnt, 0, (size_t)N * 4, stream);

  degcnt_kernel<<<(E + 255) / 256, 256, 0, stream>>>(dstA, Ew, deg, cnt, E);
  dinv_kernel<<<(N + 255) / 256, 256, 0, stream>>>(deg, N);
  scan_kernel<<<1, SCAN_T, 0, stream>>>(cnt, rowptr, wptr, N);
  fill_kernel<<<(E + 255) / 256, 256, 0, stream>>>(srcA, dstA, Ew, deg, wptr, srcs_s, what_s, E);

  long long gtot = (long long)N * 32;
  gather_kernel<<<(unsigned)((gtot + 255) / 256), 256, 0, stream>>>(rowptr, srcs_s, what_s, x, zh, N);

  dim3 gmix((N + 255) / 256, WW);
  mix_kernel<<<gmix, 256, 0, stream>>>(x, Wcheb, bcheb, zh, N);

  long long ctot = (long long)N * WW;
  conv_kernel<<<(unsigned)((ctot + 255) / 256), 256, 0, stream>>>(zh, Wconv, bconv, out, N);
}

// Round 3
// 863.756 us; speedup vs baseline: 2.5014x; 1.1168x over previous
//
#include <hip/hip_runtime.h>

#define WW 12
#define CH 32    // CIN == CMID == COUT == 32
#define KERN 3
#define SCAN_T 1024

// ---------------------------------------------------------------------------
// K1: deg[dst] += Ew  and  cnt[dst] += 1
__global__ void degcnt_kernel(const int* __restrict__ dst, const float* __restrict__ Ew,
                              float* __restrict__ deg, int* __restrict__ cnt, int E) {
  int e = blockIdx.x * blockDim.x + threadIdx.x;
  if (e < E) {
    int d = dst[e];
    atomicAdd(&deg[d], Ew[e]);
    atomicAdd(&cnt[d], 1);
  }
}

// K2: deg -> dinv in place
__global__ void dinv_kernel(float* __restrict__ deg, int N) {
  int n = blockIdx.x * blockDim.x + threadIdx.x;
  if (n < N) {
    float d = deg[n];
    deg[n] = (d > 0.f) ? rsqrtf(fmaxf(d, 1e-12f)) : 0.f;
  }
}

// K3: single-block chunked exclusive scan of cnt -> rowptr[0..N], wptr copy.
//     Each thread owns a contiguous chunk; ONE ladder pass total.
__global__ void scan_kernel(const int* __restrict__ cnt, int* __restrict__ rowptr,
                            int* __restrict__ wptr, int N) {
  __shared__ int sums[SCAN_T];
  const int tid = threadIdx.x;
  const int chunk = (N + SCAN_T - 1) / SCAN_T;
  const int lo = tid * chunk;
  const int hi = min(lo + chunk, N);

  int s = 0;
  for (int i = lo; i < hi; ++i) s += cnt[i];
  sums[tid] = s;
  __syncthreads();
  for (int ofs = 1; ofs < SCAN_T; ofs <<= 1) {
    int t = (tid >= ofs) ? sums[tid - ofs] : 0;
    __syncthreads();
    sums[tid] += t;
    __syncthreads();
  }
  int run = sums[tid] - s;  // exclusive prefix of this chunk
  for (int i = lo; i < hi; ++i) {
    rowptr[i] = run;
    wptr[i] = run;
    run += cnt[i];
  }
  if (tid == SCAN_T - 1) rowptr[N] = sums[SCAN_T - 1];
}

// K4: scatter edges into CSR slots; compute w_hat inline
__global__ void fill_kernel(const int* __restrict__ src, const int* __restrict__ dst,
                            const float* __restrict__ Ew, const float* __restrict__ dinv,
                            int* __restrict__ wptr, int* __restrict__ srcs_s,
                            float* __restrict__ what_s, int E) {
  int e = blockIdx.x * blockDim.x + threadIdx.x;
  if (e < E) {
    int s = src[e], d = dst[e];
    float wh = -dinv[s] * Ew[e] * dinv[d];
    int pos = atomicAdd(&wptr[d], 1);
    srcs_s[pos] = s;
    what_s[pos] = wh;
  }
}

// K4b: pack x (w,n,c) fp32 -> xt (n, w*32+c) bf16 (round-to-nearest-even)
__global__ void xpack_kernel(const float* __restrict__ x, unsigned short* __restrict__ xt,
                             int N) {
  long long id = (long long)blockIdx.x * blockDim.x + threadIdx.x;
  long long total = (long long)WW * N * CH;
  if (id >= total) return;
  int w = (int)(id / ((long long)N * CH));
  int rem = (int)(id % ((long long)N * CH));
  int n = rem >> 5;        // / CH
  int c = rem & 31;        // % CH
  float v = x[id];
  unsigned int u = __float_as_uint(v);
  unsigned int r = (u + 0x7FFFu + ((u >> 16) & 1u)) >> 16;  // RNE
  xt[(size_t)n * (WW * CH) + w * CH + c] = (unsigned short)r;
}

// K5: gather  z[w,n,c] = sum_{e: dst=n} what[e] * xt_bf16[src[e], w, c]
//     32 lanes = one node (lane = channel c), 12 w-planes in registers.
__global__ void gather_kernel(const int* __restrict__ rowptr, const int* __restrict__ srcs_s,
                              const float* __restrict__ what_s,
                              const unsigned short* __restrict__ xt,
                              float* __restrict__ z, int N) {
  int t = blockIdx.x * blockDim.x + threadIdx.x;
  int n = t >> 5;
  if (n >= N) return;
  int c = t & 31;
  const size_t plane = (size_t)N * CH;
  float acc[WW];
#pragma unroll
  for (int w = 0; w < WW; ++w) acc[w] = 0.f;
  int i1 = rowptr[n + 1];
  for (int i = rowptr[n]; i < i1; ++i) {
    int s = srcs_s[i];
    float wh = what_s[i];
    const unsigned short* xp = xt + (size_t)s * (WW * CH) + c;
#pragma unroll
    for (int w = 0; w < WW; ++w) {
      float xv = __uint_as_float(((unsigned int)xp[w * CH]) << 16);
      acc[w] = fmaf(wh, xv, acc[w]);
    }
  }
  float* zp = z + (size_t)n * CH + c;
#pragma unroll
  for (int w = 0; w < WW; ++w) zp[w * plane] = acc[w];
}

// K6: per (w,n):  h = bcheb[w] + x@W0[w] + z@W1[w]   (IN PLACE: zh holds z in, h out)
__global__ void mix_kernel(const float* __restrict__ x, const float* __restrict__ Wcheb,
                           const float* __restrict__ bcheb, float* __restrict__ zh, int N) {
  __shared__ float W0[CH][CH];
  __shared__ float W1[CH][CH];
  __shared__ float bs[CH];
  const int w = blockIdx.y;
  const int tid = threadIdx.x;
  for (int i = tid; i < CH * CH; i += blockDim.x) {
    W0[i >> 5][i & 31] = Wcheb[(size_t)(w * 2 + 0) * CH * CH + i];
    W1[i >> 5][i & 31] = Wcheb[(size_t)(w * 2 + 1) * CH * CH + i];
  }
  if (tid < CH) bs[tid] = bcheb[w * CH + tid];
  __syncthreads();

  const int n = blockIdx.x * blockDim.x + tid;
  if (n >= N) return;

  const float4* xp = (const float4*)(x + ((size_t)w * N + n) * CH);
  float4* zp = (float4*)(zh + ((size_t)w * N + n) * CH);

  float xv[CH], zv[CH];
#pragma unroll
  for (int i = 0; i < CH / 4; ++i) {
    float4 v = xp[i];
    xv[4 * i + 0] = v.x; xv[4 * i + 1] = v.y; xv[4 * i + 2] = v.z; xv[4 * i + 3] = v.w;
    float4 u = zp[i];
    zv[4 * i + 0] = u.x; zv[4 * i + 1] = u.y; zv[4 * i + 2] = u.z; zv[4 * i + 3] = u.w;
  }

  float ha[CH];
#pragma unroll
  for (int d = 0; d < CH; ++d) ha[d] = bs[d];
#pragma unroll
  for (int c = 0; c < CH; ++c) {
    float xc = xv[c];
    float zc = zv[c];
#pragma unroll
    for (int d = 0; d < CH; ++d) {
      ha[d] += xc * W0[c][d] + zc * W1[c][d];
    }
  }

#pragma unroll
  for (int i = 0; i < CH / 4; ++i) {
    zp[i] = make_float4(ha[4 * i], ha[4 * i + 1], ha[4 * i + 2], ha[4 * i + 3]);
  }
}

// K7: temporal conv (KER=3, pad 1) over W + bias + leaky ReLU -> out (N, W, COUT)
__global__ void conv_kernel(const float* __restrict__ h, const float* __restrict__ Wconv,
                            const float* __restrict__ bconv, float* __restrict__ out, int N) {
  __shared__ float Wc[KERN][CH][CH];  // [k][c][o]
  __shared__ float bc[CH];
  const int tid = threadIdx.x;
  for (int i = tid; i < KERN * CH * CH; i += blockDim.x) {
    int k = i / (CH * CH);
    int rem = i % (CH * CH);
    int c = rem / CH;
    int o = rem % CH;
    Wc[k][c][o] = Wconv[(o * CH + c) * KERN + k];
  }
  if (tid < CH) bc[tid] = bconv[tid];
  __syncthreads();

  long long id = (long long)blockIdx.x * blockDim.x + tid;
  if (id >= (long long)N * WW) return;
  int n = (int)(id / WW);
  int t = (int)(id % WW);

  float acc[CH];
#pragma unroll
  for (int o = 0; o < CH; ++o) acc[o] = bc[o];

#pragma unroll
  for (int k = 0; k < KERN; ++k) {
    int tt = t + k - 1;
    if (tt < 0 || tt >= WW) continue;
    const float4* hp = (const float4*)(h + ((size_t)tt * N + n) * CH);
    float hv[CH];
#pragma unroll
    for (int i = 0; i < CH / 4; ++i) {
      float4 v = hp[i];
      hv[4 * i + 0] = v.x; hv[4 * i + 1] = v.y; hv[4 * i + 2] = v.z; hv[4 * i + 3] = v.w;
    }
#pragma unroll
    for (int c = 0; c < CH; ++c) {
      float x = hv[c];
#pragma unroll
      for (int o = 0; o < CH; ++o) acc[o] += x * Wc[k][c][o];
    }
  }

  float4* op = (float4*)(out + (size_t)id * CH);
#pragma unroll
  for (int i = 0; i < CH / 4; ++i) {
    float a0 = acc[4 * i + 0], a1 = acc[4 * i + 1], a2 = acc[4 * i + 2], a3 = acc[4 * i + 3];
    a0 = (a0 >= 0.f) ? a0 : 0.01f * a0;
    a1 = (a1 >= 0.f) ? a1 : 0.01f * a1;
    a2 = (a2 >= 0.f) ? a2 : 0.01f * a2;
    a3 = (a3 >= 0.f) ? a3 : 0.01f * a3;
    op[i] = make_float4(a0, a1, a2, a3);
  }
}

// ---------------------------------------------------------------------------
extern "C" void kernel_launch(void* const* d_in, const int* in_sizes, int n_in,
                              void* d_out, int out_size, void* d_ws, size_t ws_size,
                              hipStream_t stream) {
  const float* x     = (const float*)d_in[0];
  const int*   A     = (const int*)d_in[1];
  const float* Ew    = (const float*)d_in[2];
  const float* Wcheb = (const float*)d_in[3];
  const float* bcheb = (const float*)d_in[4];
  const float* Wconv = (const float*)d_in[5];
  const float* bconv = (const float*)d_in[6];
  float* out = (float*)d_out;

  const int E = in_sizes[2];
  const int N = in_sizes[0] / (WW * CH);
  const int* srcA = A;
  const int* dstA = A + E;

  char* ws = (char*)d_ws;
  size_t off = 0;
  auto alloc = [&](size_t bytes) -> void* {
    void* p = ws + off;
    off += (bytes + 255) / 256 * 256;
    return p;
  };
  float* deg    = (float*)alloc((size_t)N * 4);        // later: dinv
  int*   cnt    = (int*)alloc((size_t)N * 4);
  int*   rowptr = (int*)alloc((size_t)(N + 1) * 4);
  int*   wptr   = (int*)alloc((size_t)N * 4);
  int*   srcs_s = (int*)alloc((size_t)E * 4);
  float* what_s = (float*)alloc((size_t)E * 4);
  unsigned short* xt = (unsigned short*)alloc((size_t)N * WW * CH * 2);
  float* zh     = (float*)alloc((size_t)WW * N * CH * 4);  // z then h (in place)
  (void)ws_size;

  hipMemsetAsync(deg, 0, (size_t)N * 4, stream);
  hipMemsetAsync(cnt, 0, (size_t)N * 4, stream);

  degcnt_kernel<<<(E + 255) / 256, 256, 0, stream>>>(dstA, Ew, deg, cnt, E);
  dinv_kernel<<<(N + 255) / 256, 256, 0, stream>>>(deg, N);
  scan_kernel<<<1, SCAN_T, 0, stream>>>(cnt, rowptr, wptr, N);
  fill_kernel<<<(E + 255) / 256, 256, 0, stream>>>(srcA, dstA, Ew, deg, wptr, srcs_s, what_s, E);

  long long xtot = (long long)WW * N * CH;
  xpack_kernel<<<(unsigned)((xtot + 255) / 256), 256, 0, stream>>>(x, xt, N);

  long long gtot = (long long)N * 32;
  gather_kernel<<<(unsigned)((gtot + 255) / 256), 256, 0, stream>>>(rowptr, srcs_s, what_s, xt, zh, N);

  dim3 gmix((N + 255) / 256, WW);
  mix_kernel<<<gmix, 256, 0, stream>>>(x, Wcheb, bcheb, zh, N);

  long long ctot = (long long)N * WW;
  conv_kernel<<<(unsigned)((ctot + 255) / 256), 256, 0, stream>>>(zh, Wconv, bconv, out, N);
}

// Round 4
// 638.922 us; speedup vs baseline: 3.3817x; 1.3519x over previous
//
#include <hip/hip_runtime.h>

#define WW 12
#define CH 32    // CIN == CMID == COUT == 32
#define KERN 3
#define SCAN_T 1024

typedef __attribute__((ext_vector_type(8))) short short8v;
typedef __attribute__((ext_vector_type(4))) float f32x4;

__device__ __forceinline__ unsigned short bf16rne(float v) {
  unsigned int u = __float_as_uint(v);
  return (unsigned short)((u + 0x7FFFu + ((u >> 16) & 1u)) >> 16);
}
__device__ __forceinline__ float bf16tof(unsigned short b) {
  return __uint_as_float(((unsigned int)b) << 16);
}

// ---------------------------------------------------------------------------
// K1: deg[dst] += Ew  and  cnt[dst] += 1
__global__ void degcnt_kernel(const int* __restrict__ dst, const float* __restrict__ Ew,
                              float* __restrict__ deg, int* __restrict__ cnt, int E) {
  int e = blockIdx.x * blockDim.x + threadIdx.x;
  if (e < E) {
    int d = dst[e];
    atomicAdd(&deg[d], Ew[e]);
    atomicAdd(&cnt[d], 1);
  }
}

// K2: deg -> dinv in place
__global__ void dinv_kernel(float* __restrict__ deg, int N) {
  int n = blockIdx.x * blockDim.x + threadIdx.x;
  if (n < N) {
    float d = deg[n];
    deg[n] = (d > 0.f) ? rsqrtf(fmaxf(d, 1e-12f)) : 0.f;
  }
}

// K3: single-block chunked exclusive scan of cnt -> rowptr[0..N], wptr copy.
__global__ void scan_kernel(const int* __restrict__ cnt, int* __restrict__ rowptr,
                            int* __restrict__ wptr, int N) {
  __shared__ int sums[SCAN_T];
  const int tid = threadIdx.x;
  const int chunk = (N + SCAN_T - 1) / SCAN_T;
  const int lo = tid * chunk;
  const int hi = min(lo + chunk, N);

  int s = 0;
  for (int i = lo; i < hi; ++i) s += cnt[i];
  sums[tid] = s;
  __syncthreads();
  for (int ofs = 1; ofs < SCAN_T; ofs <<= 1) {
    int t = (tid >= ofs) ? sums[tid - ofs] : 0;
    __syncthreads();
    sums[tid] += t;
    __syncthreads();
  }
  int run = sums[tid] - s;  // exclusive prefix of this chunk
  for (int i = lo; i < hi; ++i) {
    rowptr[i] = run;
    wptr[i] = run;
    run += cnt[i];
  }
  if (tid == SCAN_T - 1) rowptr[N] = sums[SCAN_T - 1];
}

// K4: scatter edges into CSR slots; compute w_hat inline
__global__ void fill_kernel(const int* __restrict__ src, const int* __restrict__ dst,
                            const float* __restrict__ Ew, const float* __restrict__ dinv,
                            int* __restrict__ wptr, int* __restrict__ srcs_s,
                            float* __restrict__ what_s, int E) {
  int e = blockIdx.x * blockDim.x + threadIdx.x;
  if (e < E) {
    int s = src[e], d = dst[e];
    float wh = -dinv[s] * Ew[e] * dinv[d];
    int pos = atomicAdd(&wptr[d], 1);
    srcs_s[pos] = s;
    what_s[pos] = wh;
  }
}

// K4b: pack x (w,n,c) fp32 -> xt (n, w*32+c) bf16
__global__ void xpack_kernel(const float* __restrict__ x, unsigned short* __restrict__ xt,
                             int N) {
  long long id = (long long)blockIdx.x * blockDim.x + threadIdx.x;
  long long total = (long long)WW * N * CH;
  if (id >= total) return;
  int w = (int)(id / ((long long)N * CH));
  int rem = (int)(id % ((long long)N * CH));
  int n = rem >> 5;        // / CH
  int c = rem & 31;        // % CH
  xt[(size_t)n * (WW * CH) + w * CH + c] = bf16rne(x[id]);
}

// K4c: pack weights into MFMA B-fragment order (bf16).
//  wb01: [w][m][h][lane][j]  = Wcheb[w][m][ c=(l>>4)*8+j ][ d=(l&15)+16h ]
//  wbc : [k][h][lane][j]     = Wconv[ o=(l&15)+16h ][ c=(l>>4)*8+j ][ k ]
__global__ void wpack_kernel(const float* __restrict__ Wcheb, const float* __restrict__ Wconv,
                             unsigned short* __restrict__ wb01, unsigned short* __restrict__ wbc) {
  int id = blockIdx.x * blockDim.x + threadIdx.x;
  if (id < 12 * 2 * 2 * 64 * 8) {
    int j = id & 7, l = (id >> 3) & 63, h = (id >> 9) & 1, m = (id >> 10) & 1, w = id >> 11;
    int k = ((l >> 4) << 3) + j;
    int d = (l & 15) + (h << 4);
    wb01[id] = bf16rne(Wcheb[((size_t)(w * 2 + m) * 32 + k) * 32 + d]);
  }
  int id2 = id - 24576;
  if (id2 >= 0 && id2 < 3 * 2 * 64 * 8) {
    int j = id2 & 7, l = (id2 >> 3) & 63, h = (id2 >> 9) & 1, k = id2 >> 10;
    int c = ((l >> 4) << 3) + j;
    int o = (l & 15) + (h << 4);
    wbc[id2] = bf16rne(Wconv[((size_t)(o * 32 + c)) * 3 + k]);
  }
}

// K5: gather  zt[n,w,c](bf16) = sum_{e: dst=n} what[e] * xt[src[e], w, c]
//     32 lanes = one node (lane = channel c), 12 w-planes in registers.
__global__ void gather_kernel(const int* __restrict__ rowptr, const int* __restrict__ srcs_s,
                              const float* __restrict__ what_s,
                              const unsigned short* __restrict__ xt,
                              unsigned short* __restrict__ zt, int N) {
  int t = blockIdx.x * blockDim.x + threadIdx.x;
  int n = t >> 5;
  if (n >= N) return;
  int c = t & 31;
  float acc[WW];
#pragma unroll
  for (int w = 0; w < WW; ++w) acc[w] = 0.f;
  int i1 = rowptr[n + 1];
  for (int i = rowptr[n]; i < i1; ++i) {
    int s = srcs_s[i];
    float wh = what_s[i];
    const unsigned short* xp = xt + (size_t)s * (WW * CH) + c;
#pragma unroll
    for (int w = 0; w < WW; ++w) acc[w] = fmaf(wh, bf16tof(xp[w * CH]), acc[w]);
  }
  unsigned short* zp = zt + (size_t)n * (WW * CH) + c;
#pragma unroll
  for (int w = 0; w < WW; ++w) zp[w * CH] = bf16rne(acc[w]);
}

// K6 (fused mix+conv, MFMA): per wave, 16 nodes.
//  Phase 1: for each w: H[w] = bcheb[w] + X[w]@W0[w] + Z[w]@W1[w] (bf16 -> LDS)
//  Phase 2: for each t: OUT[t] = leaky( sum_k H[t+k-1] @ Wc[k] + bconv )
//  A-frag: lane holds row=(l&15), k=(l>>4)*8+j.  D: node=(l>>4)*4+r, col=(l&15)+16h.
__global__ __launch_bounds__(256) void mc_kernel(
    const unsigned short* __restrict__ xt, const unsigned short* __restrict__ zt,
    const unsigned short* __restrict__ wb01, const unsigned short* __restrict__ wbc,
    const float* __restrict__ bcheb, const float* __restrict__ bconv,
    float* __restrict__ out, int N) {
  // [40] pad: row stride 80B keeps b128 reads 16B-aligned and spreads banks (~2-way max).
  __shared__ unsigned short hts[4][WW][16][40];
  const int wid = threadIdx.x >> 6;
  const int lane = threadIdx.x & 63;
  const int n0 = (blockIdx.x * 4 + wid) * 16;
  if (n0 >= N) return;
  const int kg = lane >> 4;
  const int arow = lane & 15;

  short8v wcf0[3], wcf1[3];
#pragma unroll
  for (int k = 0; k < 3; ++k) {
    wcf0[k] = *(const short8v*)(wbc + (((k * 2 + 0) * 64 + lane) << 3));
    wcf1[k] = *(const short8v*)(wbc + (((k * 2 + 1) * 64 + lane) << 3));
  }

  // ---- phase 1: mix ----
  for (int w = 0; w < WW; ++w) {
    const size_t fofs = (size_t)(n0 + arow) * (WW * CH) + w * CH + kg * 8;
    short8v xf = *(const short8v*)(xt + fofs);
    short8v zf = *(const short8v*)(zt + fofs);
#pragma unroll
    for (int h = 0; h < 2; ++h) {
      short8v w0f = *(const short8v*)(wb01 + ((((w * 2 + 0) * 2 + h) * 64 + lane) << 3));
      short8v w1f = *(const short8v*)(wb01 + ((((w * 2 + 1) * 2 + h) * 64 + lane) << 3));
      f32x4 acc = {0.f, 0.f, 0.f, 0.f};
      acc = __builtin_amdgcn_mfma_f32_16x16x32_bf16(xf, w0f, acc, 0, 0, 0);
      acc = __builtin_amdgcn_mfma_f32_16x16x32_bf16(zf, w1f, acc, 0, 0, 0);
      const int d = (lane & 15) + (h << 4);
      const float bias = bcheb[w * CH + d];
#pragma unroll
      for (int r = 0; r < 4; ++r) {
        hts[wid][w][kg * 4 + r][d] = bf16rne(acc[r] + bias);
      }
    }
  }
  // ---- phase 2: temporal conv ----
  for (int t = 0; t < WW; ++t) {
    f32x4 accO0 = {0.f, 0.f, 0.f, 0.f};
    f32x4 accO1 = {0.f, 0.f, 0.f, 0.f};
#pragma unroll
    for (int k = 0; k < 3; ++k) {
      int w = t + k - 1;
      if (w < 0 || w >= WW) continue;
      short8v hf = *(const short8v*)(&hts[wid][w][arow][kg * 8]);
      accO0 = __builtin_amdgcn_mfma_f32_16x16x32_bf16(hf, wcf0[k], accO0, 0, 0, 0);
      accO1 = __builtin_amdgcn_mfma_f32_16x16x32_bf16(hf, wcf1[k], accO1, 0, 0, 0);
    }
#pragma unroll
    for (int h = 0; h < 2; ++h) {
      const int o = (lane & 15) + (h << 4);
      const float bias = bconv[o];
#pragma unroll
      for (int r = 0; r < 4; ++r) {
        float v = (h ? accO1[r] : accO0[r]) + bias;
        v = (v >= 0.f) ? v : 0.01f * v;
        out[((size_t)(n0 + kg * 4 + r) * WW + t) * CH + o] = v;
      }
    }
  }
}

// ---------------------------------------------------------------------------
extern "C" void kernel_launch(void* const* d_in, const int* in_sizes, int n_in,
                              void* d_out, int out_size, void* d_ws, size_t ws_size,
                              hipStream_t stream) {
  const float* x     = (const float*)d_in[0];
  const int*   A     = (const int*)d_in[1];
  const float* Ew    = (const float*)d_in[2];
  const float* Wcheb = (const float*)d_in[3];
  const float* bcheb = (const float*)d_in[4];
  const float* Wconv = (const float*)d_in[5];
  const float* bconv = (const float*)d_in[6];
  float* out = (float*)d_out;

  const int E = in_sizes[2];
  const int N = in_sizes[0] / (WW * CH);
  const int* srcA = A;
  const int* dstA = A + E;

  char* ws = (char*)d_ws;
  size_t off = 0;
  auto alloc = [&](size_t bytes) -> void* {
    void* p = ws + off;
    off += (bytes + 255) / 256 * 256;
    return p;
  };
  float* deg    = (float*)alloc((size_t)N * 4);        // later: dinv
  int*   cnt    = (int*)alloc((size_t)N * 4);
  int*   rowptr = (int*)alloc((size_t)(N + 1) * 4);
  int*   wptr   = (int*)alloc((size_t)N * 4);
  int*   srcs_s = (int*)alloc((size_t)E * 4);
  float* what_s = (float*)alloc((size_t)E * 4);
  unsigned short* xt   = (unsigned short*)alloc((size_t)N * WW * CH * 2);
  unsigned short* zt   = (unsigned short*)alloc((size_t)N * WW * CH * 2);
  unsigned short* wb01 = (unsigned short*)alloc((size_t)24576 * 2);
  unsigned short* wbc  = (unsigned short*)alloc((size_t)3072 * 2);
  (void)ws_size;

  hipMemsetAsync(deg, 0, (size_t)N * 4, stream);
  hipMemsetAsync(cnt, 0, (size_t)N * 4, stream);

  degcnt_kernel<<<(E + 255) / 256, 256, 0, stream>>>(dstA, Ew, deg, cnt, E);
  dinv_kernel<<<(N + 255) / 256, 256, 0, stream>>>(deg, N);
  scan_kernel<<<1, SCAN_T, 0, stream>>>(cnt, rowptr, wptr, N);
  fill_kernel<<<(E + 255) / 256, 256, 0, stream>>>(srcA, dstA, Ew, deg, wptr, srcs_s, what_s, E);

  long long xtot = (long long)WW * N * CH;
  xpack_kernel<<<(unsigned)((xtot + 255) / 256), 256, 0, stream>>>(x, xt, N);
  wpack_kernel<<<(24576 + 3072 + 255) / 256, 256, 0, stream>>>(Wcheb, Wconv, wb01, wbc);

  long long gtot = (long long)N * 32;
  gather_kernel<<<(unsigned)((gtot + 255) / 256), 256, 0, stream>>>(rowptr, srcs_s, what_s, xt, zt, N);

  int ntiles = (N + 15) / 16;            // 16-node wave tiles
  int mcblocks = (ntiles + 3) / 4;       // 4 waves per block
  mc_kernel<<<mcblocks, 256, 0, stream>>>(xt, zt, wb01, wbc, bcheb, bconv, out, N);
}

// Round 5
// 577.692 us; speedup vs baseline: 3.7401x; 1.1060x over previous
//
#include <hip/hip_runtime.h>

#define WW 12
#define CH 32    // CIN == CMID == COUT == 32
#define KERN 3
#define SCAN_T 1024

typedef __attribute__((ext_vector_type(8))) short short8v;
typedef __attribute__((ext_vector_type(4))) short short4v;
typedef __attribute__((ext_vector_type(4))) float f32x4;

__device__ __forceinline__ unsigned short bf16rne(float v) {
  unsigned int u = __float_as_uint(v);
  return (unsigned short)((u + 0x7FFFu + ((u >> 16) & 1u)) >> 16);
}
__device__ __forceinline__ float bf16tof(unsigned short b) {
  return __uint_as_float(((unsigned int)b) << 16);
}
__device__ __forceinline__ float bf16tofs(short b) {
  return __uint_as_float(((unsigned int)(unsigned short)b) << 16);
}

// ---------------------------------------------------------------------------
// K1: deg[dst] += Ew  and  cnt[dst] += 1
__global__ void degcnt_kernel(const int* __restrict__ dst, const float* __restrict__ Ew,
                              float* __restrict__ deg, int* __restrict__ cnt, int E) {
  int e = blockIdx.x * blockDim.x + threadIdx.x;
  if (e < E) {
    int d = dst[e];
    atomicAdd(&deg[d], Ew[e]);
    atomicAdd(&cnt[d], 1);
  }
}

// K2: deg -> dinv in place
__global__ void dinv_kernel(float* __restrict__ deg, int N) {
  int n = blockIdx.x * blockDim.x + threadIdx.x;
  if (n < N) {
    float d = deg[n];
    deg[n] = (d > 0.f) ? rsqrtf(fmaxf(d, 1e-12f)) : 0.f;
  }
}

// K3: single-block chunked exclusive scan of cnt -> rowptr[0..N], wptr copy.
__global__ void scan_kernel(const int* __restrict__ cnt, int* __restrict__ rowptr,
                            int* __restrict__ wptr, int N) {
  __shared__ int sums[SCAN_T];
  const int tid = threadIdx.x;
  const int chunk = (N + SCAN_T - 1) / SCAN_T;
  const int lo = tid * chunk;
  const int hi = min(lo + chunk, N);

  int s = 0;
  for (int i = lo; i < hi; ++i) s += cnt[i];
  sums[tid] = s;
  __syncthreads();
  for (int ofs = 1; ofs < SCAN_T; ofs <<= 1) {
    int t = (tid >= ofs) ? sums[tid - ofs] : 0;
    __syncthreads();
    sums[tid] += t;
    __syncthreads();
  }
  int run = sums[tid] - s;  // exclusive prefix of this chunk
  for (int i = lo; i < hi; ++i) {
    rowptr[i] = run;
    wptr[i] = run;
    run += cnt[i];
  }
  if (tid == SCAN_T - 1) rowptr[N] = sums[SCAN_T - 1];
}

// K4: scatter edges into CSR slots as (src, w_hat) int2 pairs
__global__ void fill_kernel(const int* __restrict__ src, const int* __restrict__ dst,
                            const float* __restrict__ Ew, const float* __restrict__ dinv,
                            int* __restrict__ wptr, int2* __restrict__ epair, int E) {
  int e = blockIdx.x * blockDim.x + threadIdx.x;
  if (e < E) {
    int s = src[e], d = dst[e];
    float wh = -dinv[s] * Ew[e] * dinv[d];
    int pos = atomicAdd(&wptr[d], 1);
    epair[pos] = make_int2(s, __float_as_int(wh));
  }
}

// K5: pack x (w,n,c) fp32 -> xt (n, w*32+c) bf16; low ids also pack weights
//  wb01: [w][m][h][lane][j]  = Wcheb[w][m][ c=(l>>4)*8+j ][ d=(l&15)+16h ]
//  wbc : [k][h][lane][j]     = Wconv[ o=(l&15)+16h ][ c=(l>>4)*8+j ][ k ]
__global__ void pack_kernel(const float* __restrict__ x, const float* __restrict__ Wcheb,
                            const float* __restrict__ Wconv,
                            unsigned short* __restrict__ xt, unsigned short* __restrict__ wb01,
                            unsigned short* __restrict__ wbc, int N) {
  long long id = (long long)blockIdx.x * blockDim.x + threadIdx.x;
  long long total = (long long)WW * N * CH;
  if (id < total) {
    int w = (int)(id / ((long long)N * CH));
    int rem = (int)(id % ((long long)N * CH));
    int n = rem >> 5;
    int c = rem & 31;
    xt[(size_t)n * (WW * CH) + w * CH + c] = bf16rne(x[id]);
  }
  if (id < 12 * 2 * 2 * 64 * 8) {
    int i = (int)id;
    int j = i & 7, l = (i >> 3) & 63, h = (i >> 9) & 1, m = (i >> 10) & 1, w = i >> 11;
    int k = ((l >> 4) << 3) + j;
    int d = (l & 15) + (h << 4);
    wb01[i] = bf16rne(Wcheb[((size_t)(w * 2 + m) * 32 + k) * 32 + d]);
  } else if (id < 24576 + 3 * 2 * 64 * 8) {
    int i2 = (int)id - 24576;
    int j = i2 & 7, l = (i2 >> 3) & 63, h = (i2 >> 9) & 1, k = i2 >> 10;
    int c = ((l >> 4) << 3) + j;
    int o = (l & 15) + (h << 4);
    wbc[i2] = bf16rne(Wconv[((size_t)(o * 32 + c)) * 3 + k]);
  }
}

// K6: gather  zt[n,p](bf16) = sum_{e: dst=n} what[e] * xt[src[e], p]
//     32 lanes = one node; lane l owns positions p in [12l, 12l+12) of the 384-vector.
//     3x ushort4 loads per edge, unrolled x2 for MLP.
__global__ void gather_kernel(const int* __restrict__ rowptr, const int2* __restrict__ epair,
                              const unsigned short* __restrict__ xt,
                              unsigned short* __restrict__ zt, int N) {
  int t = blockIdx.x * blockDim.x + threadIdx.x;
  int n = t >> 5;
  if (n >= N) return;
  int l = t & 31;
  float acc[WW];
#pragma unroll
  for (int j = 0; j < WW; ++j) acc[j] = 0.f;
  int i = rowptr[n];
  const int i1 = rowptr[n + 1];
  for (; i + 2 <= i1; i += 2) {
    int2 e0 = epair[i];
    int2 e1 = epair[i + 1];
    const unsigned short* p0 = xt + (size_t)e0.x * (WW * CH) + l * WW;
    const unsigned short* p1 = xt + (size_t)e1.x * (WW * CH) + l * WW;
    short4v a0 = *(const short4v*)(p0);
    short4v a1 = *(const short4v*)(p0 + 4);
    short4v a2 = *(const short4v*)(p0 + 8);
    short4v b0 = *(const short4v*)(p1);
    short4v b1 = *(const short4v*)(p1 + 4);
    short4v b2 = *(const short4v*)(p1 + 8);
    float w0 = __int_as_float(e0.y);
    float w1 = __int_as_float(e1.y);
#pragma unroll
    for (int j = 0; j < 4; ++j) {
      acc[j]     = fmaf(w0, bf16tofs(a0[j]), acc[j]);
      acc[4 + j] = fmaf(w0, bf16tofs(a1[j]), acc[4 + j]);
      acc[8 + j] = fmaf(w0, bf16tofs(a2[j]), acc[8 + j]);
    }
#pragma unroll
    for (int j = 0; j < 4; ++j) {
      acc[j]     = fmaf(w1, bf16tofs(b0[j]), acc[j]);
      acc[4 + j] = fmaf(w1, bf16tofs(b1[j]), acc[4 + j]);
      acc[8 + j] = fmaf(w1, bf16tofs(b2[j]), acc[8 + j]);
    }
  }
  if (i < i1) {
    int2 e0 = epair[i];
    const unsigned short* p0 = xt + (size_t)e0.x * (WW * CH) + l * WW;
    short4v a0 = *(const short4v*)(p0);
    short4v a1 = *(const short4v*)(p0 + 4);
    short4v a2 = *(const short4v*)(p0 + 8);
    float w0 = __int_as_float(e0.y);
#pragma unroll
    for (int j = 0; j < 4; ++j) {
      acc[j]     = fmaf(w0, bf16tofs(a0[j]), acc[j]);
      acc[4 + j] = fmaf(w0, bf16tofs(a1[j]), acc[4 + j]);
      acc[8 + j] = fmaf(w0, bf16tofs(a2[j]), acc[8 + j]);
    }
  }
  unsigned short* q = zt + (size_t)n * (WW * CH) + l * WW;
  short4v o0, o1, o2;
#pragma unroll
  for (int j = 0; j < 4; ++j) {
    o0[j] = (short)bf16rne(acc[j]);
    o1[j] = (short)bf16rne(acc[4 + j]);
    o2[j] = (short)bf16rne(acc[8 + j]);
  }
  *(short4v*)(q) = o0;
  *(short4v*)(q + 4) = o1;
  *(short4v*)(q + 8) = o2;
}

// K7 (fused mix+conv, MFMA, rolling window): per wave, 16 nodes.
//  computeH(w): H[w] = bcheb[w] + X[w]@W0[w] + Z[w]@W1[w]  -> LDS ring slot w&3
//  convT(t):    OUT[t] = leaky( sum_k H[t+k-1] @ Wc[k] + bconv )
__global__ __launch_bounds__(256) void mc_kernel(
    const unsigned short* __restrict__ xt, const unsigned short* __restrict__ zt,
    const unsigned short* __restrict__ wb01, const unsigned short* __restrict__ wbc,
    const float* __restrict__ bcheb, const float* __restrict__ bconv,
    float* __restrict__ out, int N) {
  __shared__ __align__(16) unsigned short hts[4][4][16][40];  // [wave][ring][row][40-pad]
  const int wid = threadIdx.x >> 6;
  const int lane = threadIdx.x & 63;
  const int n0 = (blockIdx.x * 4 + wid) * 16;
  if (n0 >= N) return;
  const int kg = lane >> 4;
  const int arow = lane & 15;

  short8v wcf0[3], wcf1[3];
#pragma unroll
  for (int k = 0; k < 3; ++k) {
    wcf0[k] = *(const short8v*)(wbc + (((k * 2 + 0) * 64 + lane) << 3));
    wcf1[k] = *(const short8v*)(wbc + (((k * 2 + 1) * 64 + lane) << 3));
  }
  const float bc0 = bconv[arow];
  const float bc1 = bconv[arow + 16];

  auto computeH = [&](int w) {
    const size_t fofs = (size_t)(n0 + arow) * (WW * CH) + w * CH + kg * 8;
    short8v xf = *(const short8v*)(xt + fofs);
    short8v zf = *(const short8v*)(zt + fofs);
    unsigned short* hrow = &hts[wid][w & 3][0][0];
#pragma unroll
    for (int h = 0; h < 2; ++h) {
      short8v w0f = *(const short8v*)(wb01 + ((((w * 2 + 0) * 2 + h) * 64 + lane) << 3));
      short8v w1f = *(const short8v*)(wb01 + ((((w * 2 + 1) * 2 + h) * 64 + lane) << 3));
      f32x4 acc = {0.f, 0.f, 0.f, 0.f};
      acc = __builtin_amdgcn_mfma_f32_16x16x32_bf16(xf, w0f, acc, 0, 0, 0);
      acc = __builtin_amdgcn_mfma_f32_16x16x32_bf16(zf, w1f, acc, 0, 0, 0);
      const int d = arow + (h << 4);
      const float bias = bcheb[w * CH + d];
#pragma unroll
      for (int r = 0; r < 4; ++r) {
        hrow[(kg * 4 + r) * 40 + d] = bf16rne(acc[r] + bias);
      }
    }
  };

  auto convT = [&](int t) {
    f32x4 a0 = {0.f, 0.f, 0.f, 0.f};
    f32x4 a1 = {0.f, 0.f, 0.f, 0.f};
#pragma unroll
    for (int k = 0; k < 3; ++k) {
      int w = t + k - 1;
      if (w < 0 || w >= WW) continue;
      short8v hf = *(const short8v*)(&hts[wid][w & 3][arow][kg * 8]);
      a0 = __builtin_amdgcn_mfma_f32_16x16x32_bf16(hf, wcf0[k], a0, 0, 0, 0);
      a1 = __builtin_amdgcn_mfma_f32_16x16x32_bf16(hf, wcf1[k], a1, 0, 0, 0);
    }
#pragma unroll
    for (int r = 0; r < 4; ++r) {
      float v0 = a0[r] + bc0;
      float v1 = a1[r] + bc1;
      v0 = (v0 >= 0.f) ? v0 : 0.01f * v0;
      v1 = (v1 >= 0.f) ? v1 : 0.01f * v1;
      size_t o = ((size_t)(n0 + kg * 4 + r) * WW + t) * CH;
      out[o + arow] = v0;
      out[o + arow + 16] = v1;
    }
  };

  computeH(0);
  computeH(1);
  convT(0);
  for (int w = 2; w < WW; ++w) {
    computeH(w);
    convT(w - 1);
  }
  convT(WW - 1);
}

// ---------------------------------------------------------------------------
extern "C" void kernel_launch(void* const* d_in, const int* in_sizes, int n_in,
                              void* d_out, int out_size, void* d_ws, size_t ws_size,
                              hipStream_t stream) {
  const float* x     = (const float*)d_in[0];
  const int*   A     = (const int*)d_in[1];
  const float* Ew    = (const float*)d_in[2];
  const float* Wcheb = (const float*)d_in[3];
  const float* bcheb = (const float*)d_in[4];
  const float* Wconv = (const float*)d_in[5];
  const float* bconv = (const float*)d_in[6];
  float* out = (float*)d_out;

  const int E = in_sizes[2];
  const int N = in_sizes[0] / (WW * CH);
  const int* srcA = A;
  const int* dstA = A + E;

  char* ws = (char*)d_ws;
  size_t off = 0;
  auto alloc = [&](size_t bytes) -> void* {
    void* p = ws + off;
    off += (bytes + 255) / 256 * 256;
    return p;
  };
  float* deg    = (float*)alloc((size_t)N * 4);        // later: dinv
  int*   cnt    = (int*)alloc((size_t)N * 4);
  int*   rowptr = (int*)alloc((size_t)(N + 1) * 4);
  int*   wptr   = (int*)alloc((size_t)N * 4);
  int2*  epair  = (int2*)alloc((size_t)E * 8);
  unsigned short* xt   = (unsigned short*)alloc((size_t)N * WW * CH * 2);
  unsigned short* zt   = (unsigned short*)alloc((size_t)N * WW * CH * 2);
  unsigned short* wb01 = (unsigned short*)alloc((size_t)24576 * 2);
  unsigned short* wbc  = (unsigned short*)alloc((size_t)3072 * 2);
  (void)ws_size;

  // deg and cnt are adjacent in ws: one memset covers both
  hipMemsetAsync(deg, 0, (size_t)((char*)(cnt + N) - (char*)deg), stream);

  degcnt_kernel<<<(E + 255) / 256, 256, 0, stream>>>(dstA, Ew, deg, cnt, E);
  dinv_kernel<<<(N + 255) / 256, 256, 0, stream>>>(deg, N);
  scan_kernel<<<1, SCAN_T, 0, stream>>>(cnt, rowptr, wptr, N);
  fill_kernel<<<(E + 255) / 256, 256, 0, stream>>>(srcA, dstA, Ew, deg, wptr, epair, E);

  long long xtot = (long long)WW * N * CH;
  pack_kernel<<<(unsigned)((xtot + 255) / 256), 256, 0, stream>>>(x, Wcheb, Wconv, xt, wb01, wbc, N);

  long long gtot = (long long)N * 32;
  gather_kernel<<<(unsigned)((gtot + 255) / 256), 256, 0, stream>>>(rowptr, epair, xt, zt, N);

  int ntiles = (N + 15) / 16;            // 16-node wave tiles
  int mcblocks = (ntiles + 3) / 4;       // 4 waves per block
  mc_kernel<<<mcblocks, 256, 0, stream>>>(xt, zt, wb01, wbc, bcheb, bconv, out, N);
}